// Round 5
// baseline (408.897 us; speedup 1.0000x reference)
//
#include <hip/hip_runtime.h>
#include <math.h>

#define B_ 4
#define T_ 16
#define H_ 64
#define W_ 64
#define CIN 32
#define CO 64
#define NG 256   // 4*CO gate channels

typedef __attribute__((ext_vector_type(8))) short bf16x8;
typedef __attribute__((ext_vector_type(4))) float f32x4;

__device__ __forceinline__ float hsig(float z) {
    return fminf(1.f, fmaxf(0.f, 0.2f * z + 0.5f));
}

__device__ __forceinline__ unsigned short f2bf(float f) {
    union { float f; unsigned u; } v; v.f = f;
    unsigned r = v.u + 0x7FFFu + ((v.u >> 16) & 1u);   // RTNE
    return (unsigned short)(r >> 16);
}

// Transpose+convert weights once per launch:
//   wkT[kpos][n=256][k=32]        from wk (3,3,32,256)
//   wrT[kpos][q=2][n=256][k=32]   from wr (3,3,64,256), q = cin chunk of 32
__global__ void transform_weights(const float* __restrict__ wk,
                                  const float* __restrict__ wr,
                                  unsigned short* __restrict__ wkT,
                                  unsigned short* __restrict__ wrT)
{
    int i = blockIdx.x * 256 + threadIdx.x;
    if (i < 9 * 256 * 32) {
        int k = i & 31, n = (i >> 5) & 255, kpos = i >> 13;
        wkT[i] = f2bf(wk[(kpos * 32 + k) * 256 + n]);
    }
    if (i < 9 * 2 * 256 * 32) {
        int k = i & 31, n = (i >> 5) & 255, q = (i >> 13) & 1, kpos = i >> 14;
        wrT[i] = f2bf(wr[(kpos * 64 + q * 32 + k) * 256 + n]);
    }
}

// One timestep. Block = 32 px (2 rows x 16 cols) x all 256 gate-channels.
// Grid 512 = 2 blocks/CU (2 waves/SIMD) so one block's MFMA phase overlaps
// the other's staging/epilogue. Wave w: channels w*16+(lane&15), all 4 gates.
template<bool FIRST>
__global__ __launch_bounds__(256, 2)
void convlstm_step(const float* __restrict__ x,
                   const unsigned short* __restrict__ wkT,
                   const unsigned short* __restrict__ wrT,
                   const float* __restrict__ bias,
                   const float* __restrict__ gamma,
                   const float* __restrict__ beta,
                   const float* __restrict__ mean,
                   const float* __restrict__ var,
                   const unsigned short* __restrict__ hin,   // bf16 NHWC
                   unsigned short* __restrict__ hout,        // bf16 NHWC
                   float* __restrict__ cbuf,
                   float* __restrict__ out,
                   int t)
{
    __shared__ __align__(16) unsigned short sx[4 * 18 * 32];
    __shared__ __align__(16) unsigned short sh[2][4 * 18 * 32];

    const int tid = threadIdx.x;
    const int w = tid >> 6, lane = tid & 63;
    const int ln = lane & 15, kg = lane >> 4;

    const int bi = blockIdx.x;
    const int b = bi >> 7;
    const int rem = bi & 127;
    const int oy = (rem >> 2) * 2;     // 32 row-tiles of 2
    const int ox = (rem & 3) * 16;     // 4 col-tiles of 16

    const int ch = w * 16 + ln;

    // ---- pre-barrier: loads that do NOT depend on LDS (latency hides under staging)
    // per-channel constants
    const float bi0 = bias[ch], bi1 = bias[64 + ch], bi2 = bias[128 + ch], bi3 = bias[192 + ch];
    const float inv = gamma[ch] * rsqrtf(var[ch] + 1e-3f);
    const float shift = beta[ch] - mean[ch] * inv;
    // previous cell state for this thread's 8 pixels
    float cprev[2][4];
#pragma unroll
    for (int r = 0; r < 2; ++r)
#pragma unroll
        for (int reg = 0; reg < 4; ++reg) {
            if (FIRST) { cprev[r][reg] = 0.f; }
            else {
                size_t pix = ((size_t)b * H_ + oy + r) * W_ + (ox + kg * 4 + reg);
                cprev[r][reg] = cbuf[pix * CO + ch];
            }
        }
    // kpos-0 B fragments
    const unsigned short* wkp = wkT + (size_t)ch * 32 + kg * 8;
    const unsigned short* wrp = wrT + (size_t)ch * 32 + kg * 8;
    bf16x8 bx[4], bh[2][4];
#pragma unroll
    for (int g = 0; g < 4; ++g)
        bx[g] = *(const bf16x8*)(wkp + (size_t)(g * 64) * 32);
    if (!FIRST) {
#pragma unroll
        for (int q = 0; q < 2; ++q)
#pragma unroll
            for (int g = 0; g < 4; ++g)
                bh[q][g] = *(const bf16x8*)(wrp + (size_t)(q * 256 + g * 64) * 32);
    }

    // ---- stage x halo (fp32 -> bf16): 4x18 positions x 4 chunks of 8 cin ----
    for (int e = tid; e < 288; e += 256) {
        int c8 = e & 3, p = e >> 2;
        int row = p / 18, col = p - row * 18;
        int gy = oy - 1 + row, gx = ox - 1 + col;
        float4 v0 = make_float4(0.f, 0.f, 0.f, 0.f), v1 = v0;
        if ((unsigned)gy < (unsigned)H_ && (unsigned)gx < (unsigned)W_) {
            const float* p32 = &x[((((size_t)b * T_ + t) * H_ + gy) * W_ + gx) * CIN + c8 * 8];
            v0 = *(const float4*)p32; v1 = *(const float4*)(p32 + 4);
        }
        unsigned short* d = &sx[(row * 18 + col) * 32 + c8 * 8];
        d[0] = f2bf(v0.x); d[1] = f2bf(v0.y); d[2] = f2bf(v0.z); d[3] = f2bf(v0.w);
        d[4] = f2bf(v1.x); d[5] = f2bf(v1.y); d[6] = f2bf(v1.z); d[7] = f2bf(v1.w);
    }
    // ---- stage h halo (bf16 copy): 4x18 positions x 8 octs of 8 ch ----
    if (!FIRST) {
        for (int e = tid; e < 576; e += 256) {
            int o = e & 7, p = e >> 3;
            int row = p / 18, col = p - row * 18;
            int gy = oy - 1 + row, gx = ox - 1 + col;
            uint4 v = make_uint4(0u, 0u, 0u, 0u);
            if ((unsigned)gy < (unsigned)H_ && (unsigned)gx < (unsigned)W_)
                v = *(const uint4*)&hin[(((size_t)b * H_ + gy) * W_ + gx) * CO + o * 8];
            int q = o >> 2, s = o & 3;
            *(uint4*)&sh[q][(row * 18 + col) * 32 + s * 8] = v;
        }
    }
    __syncthreads();

    f32x4 acc[4][2];   // [gate][row-tile]
#pragma unroll
    for (int g = 0; g < 4; ++g)
#pragma unroll
        for (int r = 0; r < 2; ++r) acc[g][r] = (f32x4){0.f, 0.f, 0.f, 0.f};

#pragma unroll
    for (int kpos = 0; kpos < 9; ++kpos) {
        const int ky = kpos / 3, kx = kpos - ky * 3;   // compile-time after unroll
        // prefetch next kpos's B fragments
        bf16x8 nbx[4], nbh[2][4];
        if (kpos < 8) {
#pragma unroll
            for (int g = 0; g < 4; ++g)
                nbx[g] = *(const bf16x8*)(wkp + (size_t)((kpos + 1) * 256 + g * 64) * 32);
            if (!FIRST) {
#pragma unroll
                for (int q = 0; q < 2; ++q)
#pragma unroll
                    for (int g = 0; g < 4; ++g)
                        nbh[q][g] = *(const bf16x8*)(wrp + (size_t)(((kpos + 1) * 2 + q) * 256 + g * 64) * 32);
            }
        }
        // compute with current B
        bf16x8 a[2];
#pragma unroll
        for (int r = 0; r < 2; ++r)
            a[r] = *(const bf16x8*)&sx[((r + ky) * 18 + ln + kx) * 32 + kg * 8];
#pragma unroll
        for (int g = 0; g < 4; ++g)
#pragma unroll
            for (int r = 0; r < 2; ++r)
                acc[g][r] = __builtin_amdgcn_mfma_f32_16x16x32_bf16(a[r], bx[g], acc[g][r], 0, 0, 0);
        if (!FIRST) {
#pragma unroll
            for (int q = 0; q < 2; ++q) {
#pragma unroll
                for (int r = 0; r < 2; ++r)
                    a[r] = *(const bf16x8*)&sh[q][((r + ky) * 18 + ln + kx) * 32 + kg * 8];
#pragma unroll
                for (int g = 0; g < 4; ++g)
#pragma unroll
                    for (int r = 0; r < 2; ++r)
                        acc[g][r] = __builtin_amdgcn_mfma_f32_16x16x32_bf16(a[r], bh[q][g], acc[g][r], 0, 0, 0);
            }
        }
        if (kpos < 8) {
#pragma unroll
            for (int g = 0; g < 4; ++g) bx[g] = nbx[g];
            if (!FIRST) {
#pragma unroll
                for (int q = 0; q < 2; ++q)
#pragma unroll
                    for (int g = 0; g < 4; ++g) bh[q][g] = nbh[q][g];
            }
        }
    }

    // ---- epilogue: gates, state update, BN, stores ----
#pragma unroll
    for (int r = 0; r < 2; ++r) {
        const int gy = oy + r;
#pragma unroll
        for (int reg = 0; reg < 4; ++reg) {
            const int gx = ox + kg * 4 + reg;
            size_t pix = ((size_t)b * H_ + gy) * W_ + gx;
            float ig = hsig(acc[0][r][reg] + bi0);
            float fg = hsig(acc[1][r][reg] + bi1);
            float cg = tanhf(acc[2][r][reg] + bi2);
            float og = hsig(acc[3][r][reg] + bi3);
            float cv = fg * cprev[r][reg] + ig * cg;
            float hv = og * tanhf(cv);
            cbuf[pix * CO + ch] = cv;
            hout[pix * CO + ch] = f2bf(hv);
            out[((((size_t)b * T_ + t) * H_ + gy) * W_ + gx) * CO + ch] = hv * inv + shift;
        }
    }
}

extern "C" void kernel_launch(void* const* d_in, const int* in_sizes, int n_in,
                              void* d_out, int out_size, void* d_ws, size_t ws_size,
                              hipStream_t stream)
{
    (void)in_sizes; (void)n_in; (void)out_size; (void)ws_size;
    const float* x     = (const float*)d_in[0];
    const float* wk    = (const float*)d_in[1];
    const float* wr    = (const float*)d_in[2];
    const float* bias  = (const float*)d_in[3];
    const float* gamma = (const float*)d_in[4];
    const float* beta  = (const float*)d_in[5];
    const float* mean  = (const float*)d_in[6];
    const float* var   = (const float*)d_in[7];
    float* out = (float*)d_out;

    const size_t plane = (size_t)B_ * H_ * W_ * CO;           // 1,048,576 elems
    unsigned short* h0 = (unsigned short*)d_ws;               // bf16, 2 MB
    unsigned short* h1 = h0 + plane;                          // bf16, 2 MB
    float* cb = (float*)(h1 + plane);                         // fp32, 4 MB
    unsigned short* wkT = (unsigned short*)(cb + plane);      // 147 KB
    unsigned short* wrT = wkT + 9 * 256 * 32;                 // 295 KB

    transform_weights<<<576, 256, 0, stream>>>(wk, wr, wkT, wrT);

    const int nblocks = B_ * (H_ / 2) * (W_ / 16);  // 512
    for (int t = 0; t < T_; ++t) {
        const unsigned short* hin = (t & 1) ? h0 : h1;  // garbage at t==0 (unused)
        unsigned short* houtp     = (t & 1) ? h1 : h0;
        if (t == 0)
            convlstm_step<true><<<nblocks, 256, 0, stream>>>(x, wkT, wrT, bias, gamma, beta, mean, var,
                                                             hin, houtp, cb, out, t);
        else
            convlstm_step<false><<<nblocks, 256, 0, stream>>>(x, wkT, wrT, bias, gamma, beta, mean, var,
                                                              hin, houtp, cb, out, t);
    }
}